// Round 1
// baseline (188.702 us; speedup 1.0000x reference)
//
#include <hip/hip_runtime.h>
#include <stdint.h>

#define Bc 32768
#define NSTAG 2048383
#define NFULL 2097152
#define P_TOTAL (17*Bc)   // 557056 = 4352 * 128

typedef short  short8_t __attribute__((ext_vector_type(8)));
typedef __bf16 bf16x8_t __attribute__((ext_vector_type(8)));
typedef float  f32x4_t  __attribute__((ext_vector_type(4)));

__device__ __forceinline__ float bf2f(short s){
  union { unsigned u; float f; } v; v.u = ((unsigned)(unsigned short)s) << 16; return v.f;
}
__device__ __forceinline__ short f2bf(float f){
  union { float f; unsigned u; } v; v.f = f;
  unsigned r = v.u + 0x7FFFu + ((v.u >> 16) & 1u);   // RNE
  return (short)(r >> 16);
}
__device__ __forceinline__ float fast_tanh(float x){
  float e = __expf(2.0f * x);                  // v_exp_f32-based
  return 1.0f - __fdividef(2.0f, e + 1.0f);    // exact at +-inf
}

// ---- weight transpose + bf16 convert: W2t[j][k] = bf16(W2[k][j]), same for W3
__global__ void lap_convert_w(const float* __restrict__ W2, const float* __restrict__ W3,
                              short* __restrict__ W2t, short* __restrict__ W3t){
  int o = blockIdx.x * 256 + threadIdx.x;      // 0..32767
  int which = o >> 14; int e = o & 16383;
  int j = e >> 7, k = e & 127;
  const float* W = which ? W3 : W2;
  short* O = which ? W3t : W2t;
  O[e] = f2bf(W[k*128 + j]);
}

// ---- main MLP kernel: 128 points per block, fused 4-layer MLP
__global__ __launch_bounds__(256, 2)
void lap_mlp_kernel(const float* __restrict__ DATAX, const float* __restrict__ STAGX,
                    const int* __restrict__ cidx,
                    const float* __restrict__ W1, const float* __restrict__ b1,
                    const float* __restrict__ b2, const float* __restrict__ b3,
                    const float* __restrict__ W4, const float* __restrict__ b4,
                    const short* __restrict__ W2t, const short* __restrict__ W3t,
                    float* __restrict__ out)
{
  __shared__ short lds_h[128*128];   // 32 KB, activations, XOR-swizzled rows (256B stride)
  __shared__ short lds_w[128*128];   // 32 KB, weights [j][k], same swizzle
  const int t    = threadIdx.x;
  const int lane = t & 63;
  const int wv   = t >> 6;
  const int base_p = blockIdx.x * 128;

  // ---- gather: threads 0..127 fetch the 3 coords for their point.
  // x is stashed at the head of lds_w (weights not staged yet).
  float* xbuf = (float*)lds_w;
  if (t < 128) {
    int p = base_p + t;
    const float* sp;
    if (p < Bc) {
      sp = DATAX + 3*(size_t)cidx[p];
    } else {
      int q = p - Bc;
      int isNeig = (q >= 8*Bc);
      if (isNeig) q -= 8*Bc;
      int b = q >> 3, s5 = q & 7;
      int i = cidx[b];
      int ix = i >> 14, iy = (i >> 7) & 127, iz = i & 127;
      int bx = (s5 >> 2) & 1, by = (s5 >> 1) & 1, bz = s5 & 1;
      int dx, dy, dz, hi;
      if (isNeig) { dx = 2*bx-1; dy = 2*by-1; dz = 2*bz-1; hi = NFULL-1; }
      else        { dx = bx-1;   dy = by-1;   dz = bz-1;   hi = NSTAG-1; }
      // reference uses reduced-grid strides (127*127, 127) for BOTH gathers
      int f = (ix+dx)*16129 + (iy+dy)*127 + (iz+dz);
      f = f < 0 ? 0 : (f > hi ? hi : f);
      sp = (isNeig ? DATAX : STAGX) + 3*(size_t)f;
    }
    xbuf[3*t+0] = sp[0]; xbuf[3*t+1] = sp[1]; xbuf[3*t+2] = sp[2];
  }
  __syncthreads();

  // ---- layer 1 (VALU): h1 = tanh(x @ W1 + b1), write bf16 swizzled
  {
    int m = t & 127, jh = t >> 7;
    float x0 = xbuf[3*m+0], x1 = xbuf[3*m+1], x2 = xbuf[3*m+2];
    int swz = (m & 7) << 4;
    for (int c8 = 0; c8 < 8; ++c8) {
      int j0 = jh*64 + c8*8;
      short8_t pk;
      #pragma unroll
      for (int u = 0; u < 8; ++u) {
        int j = j0 + u;
        float a = b1[j] + x0*W1[j] + x1*W1[128+j] + x2*W1[256+j];
        pk[u] = f2bf(fast_tanh(a));
      }
      *(short8_t*)((char*)lds_h + m*256 + ((j0*2) ^ swz)) = pk;
    }
  }
  __syncthreads();   // xbuf dead after this; h1 visible to all

  auto stage_w = [&](const short* __restrict__ src){
    #pragma unroll
    for (int it = 0; it < 8; ++it) {
      int g = it*2048 + t*8;
      int j = g >> 7, k = g & 127;
      short8_t v = *(const short8_t*)(src + g);
      *(short8_t*)((char*)lds_w + j*256 + ((k*2) ^ ((j & 7) << 4))) = v;
    }
  };

  auto gemm_layer = [&](const float* __restrict__ bias){
    f32x4_t acc[2][8];
    #pragma unroll
    for (int rt = 0; rt < 2; ++rt)
      #pragma unroll
      for (int ct = 0; ct < 8; ++ct)
        acc[rt][ct] = (f32x4_t){0.f,0.f,0.f,0.f};
    const int rbase = wv * 32;            // wave-private 32 rows
    const int lrow = lane & 15, lk = lane >> 4;
    #pragma unroll
    for (int kk = 0; kk < 4; ++kk) {
      int kb = (kk*32 + lk*8) * 2;        // byte offset of this lane's 8 K-elems
      int r0 = rbase + lrow, r1 = rbase + 16 + lrow;
      bf16x8_t a0 = *(const bf16x8_t*)((char*)lds_h + r0*256 + (kb ^ ((r0 & 7) << 4)));
      bf16x8_t a1 = *(const bf16x8_t*)((char*)lds_h + r1*256 + (kb ^ ((r1 & 7) << 4)));
      #pragma unroll
      for (int ct = 0; ct < 8; ++ct) {
        int j = ct*16 + lrow;
        bf16x8_t bb = *(const bf16x8_t*)((char*)lds_w + j*256 + (kb ^ ((j & 7) << 4)));
        acc[0][ct] = __builtin_amdgcn_mfma_f32_16x16x32_bf16(a0, bb, acc[0][ct], 0, 0, 0);
        acc[1][ct] = __builtin_amdgcn_mfma_f32_16x16x32_bf16(a1, bb, acc[1][ct], 0, 0, 0);
      }
    }
    __syncthreads();   // safety: all fragment reads drained before h is overwritten
    // epilogue: bias + tanh -> bf16 back into this wave's rows of lds_h
    #pragma unroll
    for (int rt = 0; rt < 2; ++rt)
      #pragma unroll
      for (int ct = 0; ct < 8; ++ct) {
        int j = ct*16 + lrow;
        float bj = bias[j];
        #pragma unroll
        for (int u = 0; u < 4; ++u) {
          int r = rbase + rt*16 + lk*4 + u;   // D layout: col=lane&15, row=(lane>>4)*4+u
          float v = fast_tanh(acc[rt][ct][u] + bj);
          *(short*)((char*)lds_h + r*256 + ((j*2) ^ ((r & 7) << 4))) = f2bf(v);
        }
      }
  };

  stage_w(W2t);
  __syncthreads();
  gemm_layer(b2);
  __syncthreads();
  stage_w(W3t);
  __syncthreads();
  gemm_layer(b3);
  __syncthreads();

  // ---- layer 4 (VALU): out = h3 @ W4 + b4
  if (t < 128) {
    int m = t;
    int swz = (m & 7) << 4;
    float acc = b4[0];
    #pragma unroll
    for (int c = 0; c < 16; ++c) {
      short8_t v = *(const short8_t*)((char*)lds_h + m*256 + ((c*16) ^ swz));
      #pragma unroll
      for (int u = 0; u < 8; ++u) acc += bf2f(v[u]) * W4[c*8+u];
    }
    out[base_p + m] = acc;
  }
}

// ---- per-center loss terms + deterministic block partials (no atomics)
__global__ __launch_bounds__(256)
void lap_reduce_kernel(const int* __restrict__ cidx, const float* __restrict__ DATAF,
                       const float* __restrict__ LAPLF, const float* __restrict__ mlp,
                       float* __restrict__ partials)
{
  int b = blockIdx.x * 256 + threadIdx.x;   // exactly Bc threads
  int i = cidx[b];
  int ix = i >> 14, iy = (i >> 7) & 127, iz = i & 127;
  bool interior = (ix >= 1) && (ix < 127) && (iy >= 1) && (iy < 127) && (iz >= 1) && (iz < 127);
  float e = fabsf(mlp[b] - DATAF[i]);
  const f32x4_t* ps4 = (const f32x4_t*)(mlp + Bc   + 8*(size_t)b);
  const f32x4_t* pn4 = (const f32x4_t*)(mlp + 9*Bc + 8*(size_t)b);
  f32x4_t psa = ps4[0], psb = ps4[1], pna = pn4[0], pnb = pn4[1];
  auto term = [](float a, float bq, float c, float d){
    return fabsf(a + bq - c - d) / ((a + bq + c + d) * 1.5f);
  };
  float lap = term(pnb[3], pna[0], psb[3], psa[0])    // pn7,pn0,ps7,ps0
            + term(pna[3], pnb[0], psa[3], psb[0])    // pn3,pn4,ps3,ps4
            + term(pnb[1], pna[2], psb[1], psa[2]);   // pn5,pn2,ps5,ps2
  float dl = LAPLF[i] - lap;
  float sq = interior ? dl*dl : 0.f;
  float cn = interior ? 1.f : 0.f;
  #pragma unroll
  for (int o = 32; o > 0; o >>= 1) {
    e  += __shfl_down(e, o);
    sq += __shfl_down(sq, o);
    cn += __shfl_down(cn, o);
  }
  __shared__ float sm[4][3];
  int w = threadIdx.x >> 6;
  if ((threadIdx.x & 63) == 0) { sm[w][0]=e; sm[w][1]=sq; sm[w][2]=cn; }
  __syncthreads();
  if (threadIdx.x == 0) {
    float se=0, ss=0, sc=0;
    #pragma unroll
    for (int k = 0; k < 4; ++k){ se+=sm[k][0]; ss+=sm[k][1]; sc+=sm[k][2]; }
    partials[blockIdx.x*4+0]=se; partials[blockIdx.x*4+1]=ss; partials[blockIdx.x*4+2]=sc;
  }
}

__global__ void lap_finalize_kernel(const float* __restrict__ partials, float* __restrict__ out){
  int l = threadIdx.x;   // 64 threads
  float se=0, ss=0, sc=0;
  for (int r = l; r < 128; r += 64) {
    se += partials[4*r+0]; ss += partials[4*r+1]; sc += partials[4*r+2];
  }
  #pragma unroll
  for (int o = 32; o > 0; o >>= 1) {
    se += __shfl_down(se, o); ss += __shfl_down(ss, o); sc += __shfl_down(sc, o);
  }
  if (l == 0) out[0] = se * (1.0f/32768.f) + ss / fmaxf(sc, 1.f);
}

extern "C" void kernel_launch(void* const* d_in, const int* in_sizes, int n_in,
                              void* d_out, int out_size, void* d_ws, size_t ws_size,
                              hipStream_t stream)
{
  const float* DATAX = (const float*)d_in[0];
  const float* DATAF = (const float*)d_in[1];
  const float* STAGX = (const float*)d_in[2];
  const float* LAPLF = (const float*)d_in[3];
  const float* W1    = (const float*)d_in[4];
  const float* b1    = (const float*)d_in[5];
  const float* W2    = (const float*)d_in[6];
  const float* b2    = (const float*)d_in[7];
  const float* W3    = (const float*)d_in[8];
  const float* b3    = (const float*)d_in[9];
  const float* W4    = (const float*)d_in[10];
  const float* b4    = (const float*)d_in[11];
  const int*   cidx  = (const int*)d_in[12];
  float* out = (float*)d_out;

  char* ws = (char*)d_ws;
  float* partials = (float*)ws;                 // 128*4 floats
  short* W2t      = (short*)(ws + 4096);        // 32 KB
  short* W3t      = (short*)(ws + 36864);       // 32 KB
  float* mlp_out  = (float*)(ws + 69632);       // 557056 floats (~2.2 MB)

  lap_convert_w<<<128, 256, 0, stream>>>(W2, W3, W2t, W3t);
  lap_mlp_kernel<<<P_TOTAL/128, 256, 0, stream>>>(DATAX, STAGX, cidx,
                                                  W1, b1, b2, b3, W4, b4,
                                                  W2t, W3t, mlp_out);
  lap_reduce_kernel<<<Bc/256, 256, 0, stream>>>(cidx, DATAF, LAPLF, mlp_out, partials);
  lap_finalize_kernel<<<1, 64, 0, stream>>>(partials, out);
}